// Round 16
// baseline (47.898 us; speedup 1.0000x reference)
//
#include <hip/hip_runtime.h>
#include <cfloat>
#include <math.h>

namespace {
constexpr int   B      = 4;
constexpr int   N      = 8192;
constexpr int   KNN    = 16;
constexpr float EPSV   = 1e-12f;

// --- main kernel: 4-wave blocks, 16 rows/block, candidate-split halves ---
constexpr int   THREADS = 256;            // 4 waves
constexpr int   WAVES   = THREADS / 64;   // 4
constexpr int   RPW     = 8;              // rows per wave (waves 0&2 share rows, halves differ)
constexpr int   RPB     = 16;             // rows per block
constexpr int   BPB     = N / RPB;        // 512 blocks per batch
constexpr int   GRID    = B * BPB;        // 2048 blocks = 8192 waves
constexpr int   HALF    = N / 2;          // 4096 candidates per half
constexpr int   GG      = 4;              // 4 outer iters x 4 subgroups of 256 = 4096

// --- fallback (LDS) geometry (R5 kernel, proven) ---
constexpr int   THREADS2 = 512;
constexpr int   WAVES2   = THREADS2 / 64;
constexpr int   RPW2     = 8;
constexpr int   RPB2     = WAVES2 * RPW2; // 64
constexpr int   BPB2     = N / RPB2;      // 128
constexpr int   GRID2    = B * BPB2;      // 512
constexpr int   TILE2    = 1024;
constexpr int   NTILES2  = N / TILE2;

constexpr size_t PT4_BYTES = (size_t)B * N * sizeof(float4);   // 512 KB
}

__device__ __forceinline__ float rfl(float x) {
    return __int_as_float(__builtin_amdgcn_readfirstlane(__float_as_int(x)));
}

__device__ __forceinline__ float fast_sqrt(float x) {
#if defined(__has_builtin) && __has_builtin(__builtin_amdgcn_sqrtf)
    return __builtin_amdgcn_sqrtf(x);
#else
    return sqrtf(x);
#endif
}

// ---------- prepass: (x,y,z) -> (x,y,z,|p|^2) ----------
__global__ __launch_bounds__(256)
void knn_prep(const float* __restrict__ pc, float4* __restrict__ pt4)
{
    const int i = blockIdx.x * 256 + threadIdx.x;
    if (i < B * N) {
        const float x = pc[3 * i + 0];
        const float y = pc[3 * i + 1];
        const float z = pc[3 * i + 2];
        pt4[i] = make_float4(x, y, z, fmaf(z, z, fmaf(y, y, x * x)));
    }
}

// ---------- exact ascending sort of 4 values ----------
__device__ __forceinline__ float4 sort4(const float m[4])
{
    const float a = fminf(m[0], m[1]), b = fmaxf(m[0], m[1]);
    const float c = fminf(m[2], m[3]), d = fmaxf(m[2], m[3]);
    const float l0 = fminf(a, c), t = fmaxf(a, c);
    const float l3 = fmaxf(b, d), u = fminf(b, d);
    return make_float4(l0, fminf(t, u), fmaxf(t, u), l3);
}

// ---------- keep-4 merge of two ascending sorted-4 lists (exact) ----------
__device__ __forceinline__ float4 merge44(const float4 a, const float4 b)
{
    const float l0 = fminf(a.x, b.w), l1 = fminf(a.y, b.z);
    const float l2 = fminf(a.z, b.y), l3 = fminf(a.w, b.x);
    const float t0 = fminf(l0, l2), t2 = fmaxf(l0, l2);
    const float t1 = fminf(l1, l3), t3 = fmaxf(l1, l3);
    return make_float4(fminf(t0, t1), fmaxf(t0, t1), fminf(t2, t3), fmaxf(t2, t3));
}

// ---------- helpers reused by fallback ----------
__device__ __forceinline__ void top4_of_8(const float m[8], float L[4])
{
    const float a0 = fminf(m[0], m[1]), b0 = fmaxf(m[0], m[1]);
    const float a1 = fminf(m[2], m[3]), b1 = fmaxf(m[2], m[3]);
    const float a2 = fminf(m[4], m[5]), b2 = fmaxf(m[4], m[5]);
    const float a3 = fminf(m[6], m[7]), b3 = fmaxf(m[6], m[7]);
    const float p0 = fminf(a0, a1), xP = fmaxf(a0, a1), yP = fminf(b0, b1), p3 = fmaxf(b0, b1);
    const float p1 = fminf(xP, yP), p2 = fmaxf(xP, yP);
    const float q0 = fminf(a2, a3), xQ = fmaxf(a2, a3), yQ = fminf(b2, b3), q3 = fmaxf(b2, b3);
    const float q1 = fminf(xQ, yQ), q2 = fmaxf(xQ, yQ);
    const float l0 = fminf(p0, q3), l1 = fminf(p1, q2), l2 = fminf(p2, q1), l3 = fminf(p3, q0);
    const float t0 = fminf(l0, l2), t2 = fmaxf(l0, l2);
    const float t1 = fminf(l1, l3), t3 = fmaxf(l1, l3);
    L[0] = fminf(t0, t1); L[1] = fmaxf(t0, t1);
    L[2] = fminf(t2, t3); L[3] = fmaxf(t2, t3);
}

template <int NROWS>
__device__ __forceinline__ float merge_and_sum(float L[NROWS][4], const float* qs)
{
#pragma unroll
    for (int r = 0; r < NROWS; ++r) {
        const float p0 = __shfl_xor(L[r][0], 1, 64);
        const float p1 = __shfl_xor(L[r][1], 1, 64);
        const float p2 = __shfl_xor(L[r][2], 1, 64);
        const float p3 = __shfl_xor(L[r][3], 1, 64);
        const float l0 = fminf(L[r][0], p3), l1 = fminf(L[r][1], p2);
        const float l2 = fminf(L[r][2], p1), l3 = fminf(L[r][3], p0);
        const float t0 = fminf(l0, l2), t2 = fmaxf(l0, l2);
        const float t1 = fminf(l1, l3), t3 = fmaxf(l1, l3);
        L[r][0] = fminf(t0, t1); L[r][1] = fmaxf(t0, t1);
        L[r][2] = fminf(t2, t3); L[r][3] = fmaxf(t2, t3);
    }
    float racc[NROWS];
#pragma unroll
    for (int r = 0; r < NROWS; ++r) racc[r] = 0.0f;
#pragma unroll
    for (int k = 0; k < KNN; ++k) {
#pragma unroll
        for (int r = 0; r < NROWS; ++r) {
            float m = L[r][0];
            m = fminf(m, __shfl_xor(m, 2, 64));
            m = fminf(m, __shfl_xor(m, 4, 64));
            m = fminf(m, __shfl_xor(m, 8, 64));
            m = fminf(m, __shfl_xor(m, 16, 64));
            m = fminf(m, __shfl_xor(m, 32, 64));
            racc[r] += fast_sqrt(fmaxf(qs[r] + m, 0.0f) + EPSV);
            const bool take = (L[r][0] == m);
            L[r][0] = take ? L[r][1] : L[r][0];
            L[r][1] = take ? L[r][2] : L[r][1];
            L[r][2] = take ? L[r][3] : L[r][2];
            L[r][3] = take ? FLT_MAX : L[r][3];
        }
    }
    float wsum = 0.0f;
#pragma unroll
    for (int r = 0; r < NROWS; ++r) wsum += racc[r];
    return wsum;
}

// ---------- main kernel: candidate-split scan + 4-wave parallel merge ----------
__global__ __launch_bounds__(THREADS)
void knn_tv_split(const float4* __restrict__ pt4, float* __restrict__ outbuf)
{
    __shared__ float4 sMerge[WAVES][RPW][64];   // 32 KB
    __shared__ float  sWaveSum[WAVES];

    const int tid   = threadIdx.x;
    const int lane  = tid & 63;
    const int wave  = tid >> 6;
    const int half  = wave >> 1;              // candidate half (0/1)
    const int wrow  = wave & 1;               // row sub-block (0/1)
    const int blk   = blockIdx.x;
    const int batch = blk / BPB;
    const int row0  = (blk % BPB) * RPB + wrow * RPW;

    const float4* __restrict__ b4 = pt4 + (size_t)batch * (size_t)N;

    // query scalars -> SGPR (wave-uniform); fold -2 into q, re-add |q|^2 at pop
    float qx[RPW], qy[RPW], qz[RPW], qs[RPW];
#pragma unroll
    for (int r = 0; r < RPW; ++r) {
        const float4 q = b4[row0 + r];
        qx[r] = rfl(-2.0f * q.x);
        qy[r] = rfl(-2.0f * q.y);
        qz[r] = rfl(-2.0f * q.z);
        qs[r] = rfl(q.w);
    }

    // 4 slots/lane; stream stats: 2 waves x 64 lanes x 4 slots = 512 streams/row, depth 16
    float m0[RPW][4];
#pragma unroll
    for (int r = 0; r < RPW; ++r)
#pragma unroll
        for (int j = 0; j < 4; ++j)
            m0[r][j] = FLT_MAX;

    // scan this wave's candidate half (R14-proven, frozen): 16 subgroups of 256;
    // slot pair (q&1)*2 COMPILE-TIME (rule #20); unroll 2 outer for pipelining.
    const float4* __restrict__ p = b4 + half * HALF + lane;
#pragma unroll 2
    for (int gg = 0; gg < GG; ++gg) {
#pragma unroll
        for (int q = 0; q < 4; ++q) {
            const int off = (gg * 4 + q) * 256;
            const float4 a0 = p[off +   0];
            const float4 a1 = p[off +  64];
            const float4 a2 = p[off + 128];
            const float4 a3 = p[off + 192];
            const int s0 = (q & 1) * 2;
#pragma unroll
            for (int r = 0; r < RPW; ++r) {
                const float v0 = fmaf(a0.x, qx[r], fmaf(a0.y, qy[r], fmaf(a0.z, qz[r], a0.w)));
                const float v1 = fmaf(a1.x, qx[r], fmaf(a1.y, qy[r], fmaf(a1.z, qz[r], a1.w)));
                const float v2 = fmaf(a2.x, qx[r], fmaf(a2.y, qy[r], fmaf(a2.z, qz[r], a2.w)));
                const float v3 = fmaf(a3.x, qx[r], fmaf(a3.y, qy[r], fmaf(a3.z, qz[r], a3.w)));
                m0[r][s0 + 0] = fminf(m0[r][s0 + 0], fminf(v0, v1));   // v_min3_f32
                m0[r][s0 + 1] = fminf(m0[r][s0 + 1], fminf(v2, v3));   // v_min3_f32
            }
        }
    }

    // per-lane exact sorted-4 of its 4 stream minima, stash to LDS
#pragma unroll
    for (int r = 0; r < RPW; ++r)
        sMerge[wave][r][lane] = sort4(m0[r]);
    __syncthreads();

    // ALL 4 waves merge: wave w owns 4 rows (16-lane quarters). Producer pair for
    // this wave's rows is (wave&1, (wave&1)+2); local row = (wave>>1)*4 + quarter.
    {
        const int qq   = lane >> 4;            // quarter 0..3
        const int j    = lane & 15;
        const int src  = wave & 1;             // producer wave pair (src, src+2)
        const int rloc = ((wave >> 1) << 2) + qq;   // local row 0..7 (LDS index: ok)

        float4 G = make_float4(FLT_MAX, FLT_MAX, FLT_MAX, FLT_MAX);
#pragma unroll 1
        for (int t = 0; t < 4; ++t) {
            G = merge44(G, sMerge[src][rloc][j + 16 * t]);
            G = merge44(G, sMerge[src + 2][rloc][j + 16 * t]);
        }

        // qs for this wave's 4 rows: wave-uniform branch + lane-bit mux (static idx)
        float s0, s1, s2, s3;
        if ((wave & 2) == 0) { s0 = qs[0]; s1 = qs[1]; s2 = qs[2]; s3 = qs[3]; }
        else                 { s0 = qs[4]; s1 = qs[5]; s2 = qs[6]; s3 = qs[7]; }
        const float qsl = (lane & 16) ? s1 : s0;
        const float qsh = (lane & 16) ? s3 : s2;
        const float qsq = (lane & 32) ? qsh : qsl;

        float G0 = G.x, G1 = G.y, G2 = G.z, G3 = G.w;
        float rsum = 0.0f;
#pragma unroll
        for (int k = 0; k < KNN; ++k) {
            float m = G0;
            m = fminf(m, __shfl_xor(m, 1, 64));
            m = fminf(m, __shfl_xor(m, 2, 64));
            m = fminf(m, __shfl_xor(m, 4, 64));
            m = fminf(m, __shfl_xor(m, 8, 64));
            rsum += fast_sqrt(fmaxf(qsq + m, 0.0f) + EPSV);
            const bool take = (G0 == m);
            G0 = take ? G1 : G0;
            G1 = take ? G2 : G1;
            G2 = take ? G3 : G2;
            G3 = take ? FLT_MAX : G3;
        }

        float tot = rsum + __shfl_xor(rsum, 16, 64);
        tot += __shfl_xor(tot, 32, 64);
        if (lane == 0) sWaveSum[wave] = tot;
    }
    __syncthreads();
    if (tid == 0)
        outbuf[blk] = (sWaveSum[0] + sWaveSum[1]) + (sWaveSum[2] + sWaveSum[3]);
}

// ---------- fallback: R5's LDS-staged kernel (proven, unchanged) ----------
template <int ATOMIC>
__global__ __launch_bounds__(THREADS2)
__attribute__((amdgpu_waves_per_eu(2, 4)))
void knn_tv_lds(const float* __restrict__ pc, float* __restrict__ outbuf)
{
    __shared__ float sX[TILE2], sY[TILE2], sZ[TILE2], sS[TILE2];
    __shared__ float sWaveSum[WAVES2];

    const int tid   = threadIdx.x;
    const int lane  = tid & 63;
    const int wave  = tid >> 6;
    const int blk   = blockIdx.x;
    const int batch = blk / BPB2;
    const int row0  = (blk % BPB2) * RPB2 + wave * RPW2;

    const float* __restrict__ base = pc + (size_t)batch * (size_t)N * 3;

    float qx[RPW2], qy[RPW2], qz[RPW2], qs[RPW2];
#pragma unroll
    for (int r = 0; r < RPW2; ++r) {
        const int row = row0 + r;
        const float x = base[row * 3 + 0];
        const float y = base[row * 3 + 1];
        const float z = base[row * 3 + 2];
        qx[r] = rfl(-2.0f * x); qy[r] = rfl(-2.0f * y); qz[r] = rfl(-2.0f * z);
        qs[r] = rfl(fmaf(z, z, fmaf(y, y, x * x)));
    }

    float m0[RPW2][8];
#pragma unroll
    for (int r = 0; r < RPW2; ++r)
#pragma unroll
        for (int c = 0; c < 8; ++c) m0[r][c] = FLT_MAX;

    for (int tile = 0; tile < NTILES2; ++tile) {
        __syncthreads();
#pragma unroll
        for (int h = 0; h < 2; ++h) {
            const int p  = tid + h * THREADS2;
            const int gp = tile * TILE2 + p;
            const float x = base[gp * 3 + 0];
            const float y = base[gp * 3 + 1];
            const float z = base[gp * 3 + 2];
            sX[p] = x; sY[p] = y; sZ[p] = z;
            sS[p] = fmaf(z, z, fmaf(y, y, x * x));
        }
        __syncthreads();

#pragma unroll
        for (int grp = 0; grp < 4; ++grp) {
            const int o = grp * 256 + 4 * lane;
            const float4 CX = *(const float4*)&sX[o];
            const float4 CY = *(const float4*)&sY[o];
            const float4 CZ = *(const float4*)&sZ[o];
            const float4 CS = *(const float4*)&sS[o];
            const float cx[4] = {CX.x, CX.y, CX.z, CX.w};
            const float cy[4] = {CY.x, CY.y, CY.z, CY.w};
            const float cz[4] = {CZ.x, CZ.y, CZ.z, CZ.w};
            const float cs[4] = {CS.x, CS.y, CS.z, CS.w};
            const int jb = (grp & 1) * 4;
#pragma unroll
            for (int r = 0; r < RPW2; ++r)
#pragma unroll
                for (int i = 0; i < 4; ++i) {
                    const float v = fmaf(cx[i], qx[r], fmaf(cy[i], qy[r], fmaf(cz[i], qz[r], cs[i])));
                    m0[r][jb + i] = fminf(m0[r][jb + i], v);
                }
        }
    }

    float L[RPW2][4];
#pragma unroll
    for (int r = 0; r < RPW2; ++r) top4_of_8(m0[r], L[r]);

    const float wsum = merge_and_sum<RPW2>(L, qs);

    if (lane == 0) sWaveSum[wave] = wsum;
    __syncthreads();
    if (tid == 0) {
        float t = 0.0f;
#pragma unroll
        for (int w = 0; w < WAVES2; ++w) t += sWaveSum[w];
        if (ATOMIC) atomicAdd(outbuf, t * (1.0f / (float)(B * N)));
        else        outbuf[blk] = t;
    }
}

__global__ __launch_bounds__(256)
void knn_tv_reduce(const float* __restrict__ partial, float* __restrict__ out, int n)
{
    __shared__ float s[4];
    const int tid = threadIdx.x;
    float v = 0.0f;
    for (int i = tid; i < n; i += 256) v += partial[i];
#pragma unroll
    for (int off = 1; off < 64; off <<= 1) v += __shfl_xor(v, off, 64);
    if ((tid & 63) == 0) s[tid >> 6] = v;
    __syncthreads();
    if (tid == 0) {
        const float t = s[0] + s[1] + s[2] + s[3];
        out[0] = t * (1.0f / (float)(B * N));
    }
}

extern "C" void kernel_launch(void* const* d_in, const int* in_sizes, int n_in,
                              void* d_out, int out_size, void* d_ws, size_t ws_size,
                              hipStream_t stream)
{
    const float* pc  = (const float*)d_in[0];
    float*       out = (float*)d_out;

    if (ws_size >= PT4_BYTES + GRID * sizeof(float)) {
        float4* pt4     = (float4*)d_ws;
        float*  partial = (float*)((char*)d_ws + PT4_BYTES);
        knn_prep<<<(B * N + 255) / 256, 256, 0, stream>>>(pc, pt4);
        knn_tv_split<<<GRID, THREADS, 0, stream>>>(pt4, partial);
        knn_tv_reduce<<<1, 256, 0, stream>>>(partial, out, GRID);
    } else if (ws_size >= GRID2 * sizeof(float)) {
        float* partial = (float*)d_ws;
        knn_tv_lds<0><<<GRID2, THREADS2, 0, stream>>>(pc, partial);
        knn_tv_reduce<<<1, 256, 0, stream>>>(partial, out, GRID2);
    } else {
        hipMemsetAsync(d_out, 0, sizeof(float), stream);
        knn_tv_lds<1><<<GRID2, THREADS2, 0, stream>>>(pc, out);
    }
}